// Round 2
// baseline (1150.862 us; speedup 1.0000x reference)
//
#include <hip/hip_runtime.h>

// ---------------------------------------------------------------------------
// SharedPPOSoftModularizedMLP on MI355X (gfx950)
// B=8192, OBS=128, TASK=64, D=1024, E=8, L=4
// bf16 MFMA (16x16x32) for all GEMMs, fp32 accumulate.
// Workspace-adaptive: expert stage chunked over batch; scratch aliased.
// Third routing layer (probs[2]) is dead code in the reference -> dropped.
// ---------------------------------------------------------------------------

typedef __attribute__((ext_vector_type(8))) short short8;   // 8 x bf16 frag
typedef __attribute__((ext_vector_type(4))) float floatx4;  // MFMA acc
typedef unsigned short us;

__device__ __forceinline__ us f2bf(float f) {
  union { float f; unsigned u; } v; v.f = f;
  return (us)((v.u + 0x7FFFu + ((v.u >> 16) & 1u)) >> 16);  // RNE
}
__device__ __forceinline__ float bf2f(us h) {
  union { unsigned u; float f; } v; v.u = ((unsigned)h) << 16;
  return v.f;
}

// async global->LDS, 16B per lane; lds dest = wave-uniform base + lane*16
__device__ __forceinline__ void g2lds16(const void* g, void* l) {
  __builtin_amdgcn_global_load_lds(
      (const __attribute__((address_space(1))) void*)g,
      (__attribute__((address_space(3))) void*)l, 16, 0, 0);
}

// ---------------------------------------------------------------------------
// C[M,N] = act(A[M,K] @ Bt[N,K]^T + bias[N]); A,Bt bf16; C -> bf16 and/or f32.
// grid = (ceil(N/128), M/128, batch). block = 256. K multiple of 64.
// ---------------------------------------------------------------------------
__global__ __launch_bounds__(256)
void gemm_bt(const us* __restrict__ A, const us* __restrict__ Bt,
             const float* __restrict__ bias,
             us* __restrict__ Cb, float* __restrict__ Cf,
             int M, int N, int K,
             long long sA, long long sB, long long sBias, long long sC,
             int relu)
{
  const int e = blockIdx.z;
  const us* Ab = A + (size_t)e * sA;
  const us* Bb = Bt + (size_t)e * sB;
  const float* biasb = bias ? bias + (size_t)e * sBias : (const float*)0;

  const int m0 = blockIdx.y * 128;
  const int n0 = blockIdx.x * 128;
  const int tid = threadIdx.x;
  const int wave = tid >> 6;
  const int lane = tid & 63;
  const int wm = (wave >> 1) * 64;
  const int wn = (wave & 1) * 64;
  const int lr = lane & 15;
  const int lq = lane >> 4;

  // [128 rows][8 slabs of 16B]; physical slot = r*8 + (s ^ (r&7))
  __shared__ __align__(16) us ldsA[128 * 64];
  __shared__ __align__(16) us ldsB[128 * 64];

  floatx4 acc[4][4];
#pragma unroll
  for (int i = 0; i < 4; ++i)
#pragma unroll
    for (int j = 0; j < 4; ++j) acc[i][j] = (floatx4){0.f, 0.f, 0.f, 0.f};

  for (int k0 = 0; k0 < K; k0 += 64) {
#pragma unroll
    for (int c = 0; c < 4; ++c) {
      int slot = c * 256 + tid;               // physical 16B chunk
      int r = slot >> 3;
      int s = (slot & 7) ^ (r & 7);           // logical slab (XOR swizzle)
      int ubase = (c * 256 + wave * 64) * 8;  // wave-uniform LDS base (us)
      const us* ga = Ab + (size_t)(m0 + r) * K + k0 + s * 8;
      g2lds16(ga, ldsA + ubase);
      int nrow = n0 + r; if (nrow > N - 1) nrow = N - 1;  // clamp (N<128)
      const us* gb = Bb + (size_t)nrow * K + k0 + s * 8;
      g2lds16(gb, ldsB + ubase);
    }
    __syncthreads();

#pragma unroll
    for (int kk = 0; kk < 2; ++kk) {
      short8 af[4], bfr[4];
#pragma unroll
      for (int t = 0; t < 4; ++t) {
        int m = wm + t * 16 + lr;
        int s = kk * 4 + lq;
        af[t]  = *(const short8*)(ldsA + (size_t)(m * 8 + (s ^ (m & 7))) * 8);
        int n = wn + t * 16 + lr;
        bfr[t] = *(const short8*)(ldsB + (size_t)(n * 8 + (s ^ (n & 7))) * 8);
      }
#pragma unroll
      for (int mt = 0; mt < 4; ++mt)
#pragma unroll
        for (int nt = 0; nt < 4; ++nt)
          acc[mt][nt] = __builtin_amdgcn_mfma_f32_16x16x32_bf16(
              af[mt], bfr[nt], acc[mt][nt], 0, 0, 0);
    }
    __syncthreads();
  }

  // epilogue: C/D layout col=lane&15, row=lq*4+r
#pragma unroll
  for (int nt = 0; nt < 4; ++nt) {
    int col = n0 + wn + nt * 16 + lr;
    if (col >= N) continue;
    float bv = biasb ? biasb[col] : 0.f;
#pragma unroll
    for (int mt = 0; mt < 4; ++mt) {
      int row = m0 + wm + mt * 16 + lq * 4;
#pragma unroll
      for (int r = 0; r < 4; ++r) {
        float v = acc[mt][nt][r] + bv;
        if (relu) v = fmaxf(v, 0.f);
        size_t idx = (size_t)e * sC + (size_t)(row + r) * N + col;
        if (Cf) Cf[idx] = v;
        if (Cb) Cb[idx] = f2bf(v);
      }
    }
  }
}

// fp32 [R,C] -> bf16 [C,R] (batched)
__global__ __launch_bounds__(256)
void transpose_bf16(const float* __restrict__ in, us* __restrict__ out,
                    int R, int C, long long inStride, long long outStride)
{
  const int b = blockIdx.z;
  in  += (size_t)b * inStride;
  out += (size_t)b * outStride;
  __shared__ float tile[32][33];
  const int tx = threadIdx.x & 31, ty = threadIdx.x >> 5;
  const int c0 = blockIdx.x * 32, r0 = blockIdx.y * 32;
#pragma unroll
  for (int i = 0; i < 4; ++i) {
    int r = r0 + ty + i * 8, c = c0 + tx;
    tile[ty + i * 8][tx] = (r < R && c < C) ? in[(size_t)r * C + c] : 0.f;
  }
  __syncthreads();
#pragma unroll
  for (int i = 0; i < 4; ++i) {
    int c = c0 + ty + i * 8, r = r0 + tx;
    if (c < C && r < R) out[(size_t)c * R + r] = f2bf(tile[tx][ty + i * 8]);
  }
}

// split x(B,192) -> obs bf16 (B,128), task bf16 (B,64)
__global__ __launch_bounds__(256)
void split_convert_x(const float* __restrict__ x, us* __restrict__ obs,
                     us* __restrict__ task, int total)
{
  int i = blockIdx.x * 256 + threadIdx.x;
  if (i >= total) return;
  int b = i / 192, c = i - b * 192;
  us v = f2bf(x[i]);
  if (c < 128) obs[(size_t)b * 128 + c] = v;
  else         task[(size_t)b * 64 + (c - 128)] = v;
}

// r_in = f_obs * z ; zr = relu(r_in).  NOTE: zr may alias z (in-place safe).
__global__ __launch_bounds__(256)
void ew_rin_kernel(const us* fobs, const us* z, us* r_in, us* zr, int n4)
{
  int i = blockIdx.x * 256 + threadIdx.x;
  if (i >= n4) return;
  ushort4 fv = ((const ushort4*)fobs)[i];
  ushort4 zv = ((const ushort4*)z)[i];
  float r0 = bf2f(fv.x) * bf2f(zv.x);
  float r1 = bf2f(fv.y) * bf2f(zv.y);
  float r2 = bf2f(fv.z) * bf2f(zv.z);
  float r3 = bf2f(fv.w) * bf2f(zv.w);
  ushort4 rv = { f2bf(r0), f2bf(r1), f2bf(r2), f2bf(r3) };
  ushort4 bv = { f2bf(fmaxf(r0,0.f)), f2bf(fmaxf(r1,0.f)),
                 f2bf(fmaxf(r2,0.f)), f2bf(fmaxf(r3,0.f)) };
  ((ushort4*)r_in)[i] = rv;
  ((ushort4*)zr)[i] = bv;
}

// out = relu(u * r_in).  NOTE: out may alias u (in-place safe).
__global__ __launch_bounds__(256)
void ew_umix_kernel(const us* u, const us* r_in, us* out, int n4)
{
  int i = blockIdx.x * 256 + threadIdx.x;
  if (i >= n4) return;
  ushort4 uv = ((const ushort4*)u)[i];
  ushort4 rv = ((const ushort4*)r_in)[i];
  ushort4 bv = { f2bf(fmaxf(bf2f(uv.x) * bf2f(rv.x), 0.f)),
                 f2bf(fmaxf(bf2f(uv.y) * bf2f(rv.y), 0.f)),
                 f2bf(fmaxf(bf2f(uv.z) * bf2f(rv.z), 0.f)),
                 f2bf(fmaxf(bf2f(uv.w) * bf2f(rv.w), 0.f)) };
  ((ushort4*)out)[i] = bv;
}

// softmax over groups of 8 contiguous floats
__global__ __launch_bounds__(256)
void softmax8_kernel(const float* __restrict__ p, float* __restrict__ probs, int total)
{
  int i = blockIdx.x * 256 + threadIdx.x;
  if (i >= total) return;
  const float4 lo = *(const float4*)(p + (size_t)i * 8);
  const float4 hi = *(const float4*)(p + (size_t)i * 8 + 4);
  float v[8] = { lo.x, lo.y, lo.z, lo.w, hi.x, hi.y, hi.z, hi.w };
  float m = v[0];
#pragma unroll
  for (int j = 1; j < 8; ++j) m = fmaxf(m, v[j]);
  float s = 0.f;
#pragma unroll
  for (int j = 0; j < 8; ++j) { v[j] = __expf(v[j] - m); s += v[j]; }
  float inv = 1.f / s;
  float4 olo = { v[0]*inv, v[1]*inv, v[2]*inv, v[3]*inv };
  float4 ohi = { v[4]*inv, v[5]*inv, v[6]*inv, v[7]*inv };
  *(float4*)(probs + (size_t)i * 8)     = olo;
  *(float4*)(probs + (size_t)i * 8 + 4) = ohi;
}

// xx[i,bl,d] = sum_j P[bg,i,j]*he[j,bl,d]; block per local b; 4 d/thread
__global__ __launch_bounds__(256)
void mix_kernel(const us* __restrict__ he, const float* __restrict__ probs_l,
                us* __restrict__ xx, int b0, int chunkB)
{
  const int bl = blockIdx.x;
  const int bg = b0 + bl;
  __shared__ float P[64];
  if (threadIdx.x < 64) P[threadIdx.x] = probs_l[(size_t)bg * 64 + threadIdx.x];
  __syncthreads();
  const int t = threadIdx.x;
  const size_t base = (size_t)bl * 1024 + (size_t)t * 4;
  const size_t es = (size_t)chunkB * 1024;
  float hv[8][4];
#pragma unroll
  for (int j = 0; j < 8; ++j) {
    ushort4 h4 = *(const ushort4*)(he + (size_t)j * es + base);
    hv[j][0] = bf2f(h4.x); hv[j][1] = bf2f(h4.y);
    hv[j][2] = bf2f(h4.z); hv[j][3] = bf2f(h4.w);
  }
#pragma unroll
  for (int i = 0; i < 8; ++i) {
    float o0 = 0.f, o1 = 0.f, o2 = 0.f, o3 = 0.f;
#pragma unroll
    for (int j = 0; j < 8; ++j) {
      float pij = P[i * 8 + j];
      o0 += pij * hv[j][0]; o1 += pij * hv[j][1];
      o2 += pij * hv[j][2]; o3 += pij * hv[j][3];
    }
    ushort4 ov = { f2bf(o0), f2bf(o1), f2bf(o2), f2bf(o3) };
    *(ushort4*)(xx + (size_t)i * es + base) = ov;
  }
}

// mu[bg,o]=sum_e sum_d xx[e,bl,d]*a_W[e,d,o]+sum_e a_b; values likewise.
// out = [mu (B,8) | values (B)]
__global__ __launch_bounds__(256)
void head_kernel(const us* __restrict__ xx,
                 const float* __restrict__ aW, const float* __restrict__ ab,
                 const float* __restrict__ cW, const float* __restrict__ cb,
                 float* __restrict__ out, int b0, int chunkB, int B)
{
  const int bl = blockIdx.x;
  const int bg = b0 + bl;
  const int t = threadIdx.x;
  const int lane = t & 63, wave = t >> 6;
  const size_t es = (size_t)chunkB * 1024;
  float acc[9];
#pragma unroll
  for (int o = 0; o < 9; ++o) acc[o] = 0.f;

  for (int e = 0; e < 8; ++e) {
    ushort4 x4 = *(const ushort4*)(xx + (size_t)e * es + (size_t)bl * 1024 + (size_t)t * 4);
    float xf[4] = { bf2f(x4.x), bf2f(x4.y), bf2f(x4.z), bf2f(x4.w) };
    float4 cw = *(const float4*)(cW + (size_t)e * 1024 + (size_t)t * 4);
    acc[8] += xf[0]*cw.x + xf[1]*cw.y + xf[2]*cw.z + xf[3]*cw.w;
    const float* awp = aW + ((size_t)e * 1024 + (size_t)t * 4) * 8;
#pragma unroll
    for (int dd = 0; dd < 4; ++dd) {
      float xd = xf[dd];
      float4 lo4 = *(const float4*)(awp + dd * 8);
      float4 hi4 = *(const float4*)(awp + dd * 8 + 4);
      acc[0] += xd * lo4.x; acc[1] += xd * lo4.y;
      acc[2] += xd * lo4.z; acc[3] += xd * lo4.w;
      acc[4] += xd * hi4.x; acc[5] += xd * hi4.y;
      acc[6] += xd * hi4.z; acc[7] += xd * hi4.w;
    }
  }
#pragma unroll
  for (int o = 0; o < 9; ++o) {
    float v = acc[o];
    for (int off = 32; off > 0; off >>= 1) v += __shfl_down(v, off, 64);
    acc[o] = v;
  }
  __shared__ float part[4][9];
  if (lane == 0) {
#pragma unroll
    for (int o = 0; o < 9; ++o) part[wave][o] = acc[o];
  }
  __syncthreads();
  if (t < 9) {
    float s = part[0][t] + part[1][t] + part[2][t] + part[3][t];
    float bsum = 0.f;
    if (t < 8) { for (int e = 0; e < 8; ++e) bsum += ab[e * 8 + t]; }
    else       { for (int e = 0; e < 8; ++e) bsum += cb[e]; }
    s += bsum;
    if (t < 8) out[(size_t)bg * 8 + t] = s;
    else       out[(size_t)B * 8 + bg] = s;
  }
}

// ---------------------------------------------------------------------------
extern "C" void kernel_launch(void* const* d_in, const int* in_sizes, int n_in,
                              void* d_out, int out_size, void* d_ws, size_t ws_size,
                              hipStream_t stream)
{
  const float* x   = (const float*)d_in[0];
  const float* sW1 = (const float*)d_in[1];
  const float* sb1 = (const float*)d_in[2];
  const float* sW2 = (const float*)d_in[3];
  const float* sb2 = (const float*)d_in[4];
  const float* sW3 = (const float*)d_in[5];
  const float* sb3 = (const float*)d_in[6];
  const float* tW  = (const float*)d_in[7];
  const float* tb  = (const float*)d_in[8];
  const float* rdW = (const float*)d_in[9];
  const float* rdb = (const float*)d_in[10];
  const float* ruW = (const float*)d_in[11];
  const float* rub = (const float*)d_in[12];
  const float* eW  = (const float*)d_in[13];
  const float* eb  = (const float*)d_in[14];
  const float* aW  = (const float*)d_in[15];
  const float* ab  = (const float*)d_in[16];
  const float* cW  = (const float*)d_in[17];
  const float* cb  = (const float*)d_in[18];
  float* out = (float*)d_out;

  const int B = 8192;
  const size_t BD = (size_t)B * 1024;
  char* ws = (char*)d_ws;

  // ---- arena: persistent region -------------------------------------------
  size_t o = 0;
  auto take = [&](size_t bytes) { size_t r = o; o = (o + bytes + 255) & ~(size_t)255; return r; };
  const size_t off_s1t  = take((size_t)512 * 128 * 2);
  const size_t off_s2t  = take((size_t)512 * 512 * 2);
  const size_t off_s3t  = take((size_t)1024 * 512 * 2);
  const size_t off_tWt  = take((size_t)1024 * 64 * 2);
  const size_t off_rdt  = take((size_t)2 * 64 * 1024 * 2);   // layers 0,1 only
  const size_t off_rut  = take((size_t)1024 * 64 * 2);       // layer 0 only
  const size_t off_eWt  = take((size_t)16 * 1024 * 1024 * 2);
  const size_t off_fobs = take(BD * 2);
  const size_t off_probs= take((size_t)2 * B * 64 * 4);
  const size_t P0 = o;
  // ---- scratch overlays (routing phase) -----------------------------------
  const size_t off_rin  = P0;                 // also h1
  const size_t off_rbuf = off_rin + BD * 2;   // also h2, z, u
  const size_t off_pbuf = off_rbuf + BD * 2;
  const size_t off_pbf  = off_pbuf + (size_t)2 * B * 64 * 4;
  const size_t off_obs  = off_pbf + (size_t)2 * B * 64 * 2;
  const size_t off_task = off_obs + (size_t)B * 128 * 2;
  const size_t routing_end = off_task + (size_t)B * 64 * 2;

  // ---- expert-stage chunk selection (he/xx overlay scratch at P0) ---------
  int chunk = 0;
  const int cands[4] = {8192, 4096, 2048, 1024};
  for (int i = 0; i < 4; ++i) {
    size_t need = P0 + (size_t)cands[i] * 32768;  // he + xx
    if (need <= ws_size) { chunk = cands[i]; break; }
  }
  if (!chunk || routing_end > ws_size) return;  // workspace too small

  us* s1t  = (us*)(ws + off_s1t);
  us* s2t  = (us*)(ws + off_s2t);
  us* s3t  = (us*)(ws + off_s3t);
  us* tWt  = (us*)(ws + off_tWt);
  us* rdt  = (us*)(ws + off_rdt);
  us* rut  = (us*)(ws + off_rut);
  us* eWt  = (us*)(ws + off_eWt);
  us* fobs = (us*)(ws + off_fobs);
  float* probs = (float*)(ws + off_probs);
  us* rin  = (us*)(ws + off_rin);
  us* rbuf = (us*)(ws + off_rbuf);
  float* pbuf = (float*)(ws + off_pbuf);
  us* pbf  = (us*)(ws + off_pbf);
  us* obs_bf  = (us*)(ws + off_obs);
  us* task_bf = (us*)(ws + off_task);
  us* h1 = rin;    // alias: dead before rin written
  us* h2 = rbuf;   // alias: dead before z written
  us* he = (us*)(ws + P0);
  us* xx = (us*)(ws + P0 + (size_t)chunk * 16384);

  // ---- weight conversion / input split ------------------------------------
  split_convert_x<<<dim3((B * 192 + 255) / 256), 256, 0, stream>>>(x, obs_bf, task_bf, B * 192);
  transpose_bf16<<<dim3(16, 4, 1),  256, 0, stream>>>(sW1, s1t, 128, 512, 0, 0);
  transpose_bf16<<<dim3(16, 16, 1), 256, 0, stream>>>(sW2, s2t, 512, 512, 0, 0);
  transpose_bf16<<<dim3(32, 16, 1), 256, 0, stream>>>(sW3, s3t, 512, 1024, 0, 0);
  transpose_bf16<<<dim3(32, 2, 1),  256, 0, stream>>>(tW, tWt, 64, 1024, 0, 0);
  transpose_bf16<<<dim3(2, 32, 2),  256, 0, stream>>>(rdW, rdt, 1024, 64, 65536, 65536);
  transpose_bf16<<<dim3(32, 2, 1),  256, 0, stream>>>(ruW, rut, 64, 1024, 0, 0);
  transpose_bf16<<<dim3(32, 32, 16), 256, 0, stream>>>(eW, eWt, 1024, 1024, 1048576, 1048576);

  const int n4 = (int)(BD / 4);
  const int ewg = (n4 + 255) / 256;

  // ---- shared MLP ---------------------------------------------------------
  gemm_bt<<<dim3(4, 64, 1), 256, 0, stream>>>(obs_bf, s1t, sb1, h1, (float*)0,
      B, 512, 128, 0, 0, 0, 0, 1);
  gemm_bt<<<dim3(4, 64, 1), 256, 0, stream>>>(h1, s2t, sb2, h2, (float*)0,
      B, 512, 512, 0, 0, 0, 0, 1);
  gemm_bt<<<dim3(8, 64, 1), 256, 0, stream>>>(h2, s3t, sb3, fobs, (float*)0,
      B, 1024, 512, 0, 0, 0, 0, 0);
  gemm_bt<<<dim3(8, 64, 1), 256, 0, stream>>>(task_bf, tWt, tb, rbuf, (float*)0,
      B, 1024, 64, 0, 0, 0, 0, 1);                 // z -> rbuf
  ew_rin_kernel<<<dim3(ewg), 256, 0, stream>>>(fobs, rbuf, rin, rbuf, n4);  // in-place

  // ---- routing (layers 0,1; layer 2 is dead code in the reference) --------
  gemm_bt<<<dim3(1, 64, 1), 256, 0, stream>>>(rbuf, rdt, rdb, pbf, pbuf,
      B, 64, 1024, 0, 0, 0, 0, 0);                 // p0
  gemm_bt<<<dim3(8, 64, 1), 256, 0, stream>>>(pbf, rut, rub, rbuf, (float*)0,
      B, 1024, 64, 0, 0, 0, 0, 0);                 // u -> rbuf
  ew_umix_kernel<<<dim3(ewg), 256, 0, stream>>>(rbuf, rin, rbuf, n4);       // in-place
  gemm_bt<<<dim3(1, 64, 1), 256, 0, stream>>>(rbuf, rdt + 65536, rdb + 64,
      pbf + (size_t)B * 64, pbuf + (size_t)B * 64, B, 64, 1024, 0, 0, 0, 0, 0);  // p1
  softmax8_kernel<<<dim3((2 * B * 8 + 255) / 256), 256, 0, stream>>>(pbuf, probs, 2 * B * 8);

  // ---- expert stage, chunked over batch -----------------------------------
  const long long sHE = (long long)chunk * 1024;
  for (int b0 = 0; b0 < B; b0 += chunk) {
    gemm_bt<<<dim3(8, chunk / 128, 8), 256, 0, stream>>>(
        fobs + (size_t)b0 * 1024, eWt, eb, he, (float*)0,
        chunk, 1024, 1024, 0, 1048576, 1024, sHE, 1);
    mix_kernel<<<dim3(chunk), 256, 0, stream>>>(he, probs, xx, b0, chunk);
    gemm_bt<<<dim3(8, chunk / 128, 8), 256, 0, stream>>>(
        xx, eWt + (size_t)8 * 1048576, eb + 8192, he, (float*)0,
        chunk, 1024, 1024, sHE, 1048576, 1024, sHE, 1);
    mix_kernel<<<dim3(chunk), 256, 0, stream>>>(he, probs + (size_t)B * 64, xx, b0, chunk);
    head_kernel<<<dim3(chunk), 256, 0, stream>>>(xx, aW, ab, cW, cb, out, b0, chunk, B);
  }
}

// Round 3
// 927.898 us; speedup vs baseline: 1.2403x; 1.2403x over previous
//
#include <hip/hip_runtime.h>

// ---------------------------------------------------------------------------
// SharedPPOSoftModularizedMLP on MI355X (gfx950)
// B=8192, OBS=128, TASK=64, D=1024, E=8, L=4
// bf16 MFMA (16x16x32) for all GEMMs, fp32 accumulate.
// R3: heads reformulated as M=8192,N=9,K=8192 GEMM (split-K=4, f32 atomics);
//     routing rd-GEMMs (N=64) also split-K=4 for CU occupancy.
// ---------------------------------------------------------------------------

typedef __attribute__((ext_vector_type(8))) short short8;   // 8 x bf16 frag
typedef __attribute__((ext_vector_type(4))) float floatx4;  // MFMA acc
typedef unsigned short us;

__device__ __forceinline__ us f2bf(float f) {
  union { float f; unsigned u; } v; v.f = f;
  return (us)((v.u + 0x7FFFu + ((v.u >> 16) & 1u)) >> 16);  // RNE
}
__device__ __forceinline__ float bf2f(us h) {
  union { unsigned u; float f; } v; v.u = ((unsigned)h) << 16;
  return v.f;
}

// async global->LDS, 16B per lane; lds dest = wave-uniform base + lane*16
__device__ __forceinline__ void g2lds16(const void* g, void* l) {
  __builtin_amdgcn_global_load_lds(
      (const __attribute__((address_space(1))) void*)g,
      (__attribute__((address_space(3))) void*)l, 16, 0, 0);
}

// ---------------------------------------------------------------------------
// C[M,N] = act(A[M,K]@Bt[N,K]^T + bias[N]); A,Bt bf16; C -> bf16 and/or f32.
// grid=(ceil(N/128), M/128, Z). Z = expert (normal) or k-chunk (splitK mode:
// Ab=A+z*sA, Bb=Bt+z*sB, atomicAdd into Cf, no bias/relu/Cb).
// lda/ldb = row strides (elements); K = k-loop extent (multiple of 64).
// ---------------------------------------------------------------------------
__global__ __launch_bounds__(256)
void gemm_bt(const us* __restrict__ A, const us* __restrict__ Bt,
             const float* __restrict__ bias,
             us* __restrict__ Cb, float* __restrict__ Cf,
             int M, int N, int K, int lda, int ldb,
             long long sA, long long sB, long long sBias, long long sC,
             int relu, int atomic)
{
  const int e = blockIdx.z;
  const us* Ab = A + (size_t)e * sA;
  const us* Bb = Bt + (size_t)e * sB;
  const float* biasb = bias ? bias + (size_t)e * sBias : (const float*)0;

  const int m0 = blockIdx.y * 128;
  const int n0 = blockIdx.x * 128;
  const int tid = threadIdx.x;
  const int wave = tid >> 6;
  const int lane = tid & 63;
  const int wm = (wave >> 1) * 64;
  const int wn = (wave & 1) * 64;
  const int lr = lane & 15;
  const int lq = lane >> 4;

  // [128 rows][8 slabs of 16B]; physical slot = r*8 + (s ^ (r&7))
  __shared__ __align__(16) us ldsA[128 * 64];
  __shared__ __align__(16) us ldsB[128 * 64];

  floatx4 acc[4][4];
#pragma unroll
  for (int i = 0; i < 4; ++i)
#pragma unroll
    for (int j = 0; j < 4; ++j) acc[i][j] = (floatx4){0.f, 0.f, 0.f, 0.f};

  for (int k0 = 0; k0 < K; k0 += 64) {
#pragma unroll
    for (int c = 0; c < 4; ++c) {
      int slot = c * 256 + tid;               // physical 16B chunk
      int r = slot >> 3;
      int s = (slot & 7) ^ (r & 7);           // logical slab (XOR swizzle)
      int ubase = (c * 256 + wave * 64) * 8;  // wave-uniform LDS base (us)
      const us* ga = Ab + (size_t)(m0 + r) * lda + k0 + s * 8;
      g2lds16(ga, ldsA + ubase);
      int nrow = n0 + r; if (nrow > N - 1) nrow = N - 1;  // clamp (N<128)
      const us* gb = Bb + (size_t)nrow * ldb + k0 + s * 8;
      g2lds16(gb, ldsB + ubase);
    }
    __syncthreads();

#pragma unroll
    for (int kk = 0; kk < 2; ++kk) {
      short8 af[4], bfr[4];
#pragma unroll
      for (int t = 0; t < 4; ++t) {
        int m = wm + t * 16 + lr;
        int s = kk * 4 + lq;
        af[t]  = *(const short8*)(ldsA + (size_t)(m * 8 + (s ^ (m & 7))) * 8);
        int n = wn + t * 16 + lr;
        bfr[t] = *(const short8*)(ldsB + (size_t)(n * 8 + (s ^ (n & 7))) * 8);
      }
#pragma unroll
      for (int mt = 0; mt < 4; ++mt)
#pragma unroll
        for (int nt = 0; nt < 4; ++nt)
          acc[mt][nt] = __builtin_amdgcn_mfma_f32_16x16x32_bf16(
              af[mt], bfr[nt], acc[mt][nt], 0, 0, 0);
    }
    __syncthreads();
  }

  // epilogue: C/D layout col=lane&15, row=lq*4+r
#pragma unroll
  for (int nt = 0; nt < 4; ++nt) {
    int col = n0 + wn + nt * 16 + lr;
    if (col >= N) continue;
    float bv = biasb ? biasb[col] : 0.f;
#pragma unroll
    for (int mt = 0; mt < 4; ++mt) {
      int row = m0 + wm + mt * 16 + lq * 4;
#pragma unroll
      for (int r = 0; r < 4; ++r) {
        float v = acc[mt][nt][r] + bv;
        if (relu) v = fmaxf(v, 0.f);
        size_t idx = (size_t)e * sC + (size_t)(row + r) * N + col;
        if (atomic) { atomicAdd(Cf + (size_t)(row + r) * N + col, v); continue; }
        if (Cf) Cf[idx] = v;
        if (Cb) Cb[idx] = f2bf(v);
      }
    }
  }
}

// fp32 [R,C] -> bf16 [C,R] (batched)
__global__ __launch_bounds__(256)
void transpose_bf16(const float* __restrict__ in, us* __restrict__ out,
                    int R, int C, long long inStride, long long outStride)
{
  const int b = blockIdx.z;
  in  += (size_t)b * inStride;
  out += (size_t)b * outStride;
  __shared__ float tile[32][33];
  const int tx = threadIdx.x & 31, ty = threadIdx.x >> 5;
  const int c0 = blockIdx.x * 32, r0 = blockIdx.y * 32;
#pragma unroll
  for (int i = 0; i < 4; ++i) {
    int r = r0 + ty + i * 8, c = c0 + tx;
    tile[ty + i * 8][tx] = (r < R && c < C) ? in[(size_t)r * C + c] : 0.f;
  }
  __syncthreads();
#pragma unroll
  for (int i = 0; i < 4; ++i) {
    int c = c0 + ty + i * 8, r = r0 + tx;
    if (c < C && r < R) out[(size_t)c * R + r] = f2bf(tile[tx][ty + i * 8]);
  }
}

// split x(B,192) -> obs bf16 (B,128), task bf16 (B,64)
__global__ __launch_bounds__(256)
void split_convert_x(const float* __restrict__ x, us* __restrict__ obs,
                     us* __restrict__ task, int total)
{
  int i = blockIdx.x * 256 + threadIdx.x;
  if (i >= total) return;
  int b = i / 192, c = i - b * 192;
  us v = f2bf(x[i]);
  if (c < 128) obs[(size_t)b * 128 + c] = v;
  else         task[(size_t)b * 64 + (c - 128)] = v;
}

__global__ __launch_bounds__(256)
void zero_f32(float* __restrict__ p, int n)
{
  int i = blockIdx.x * 256 + threadIdx.x;
  if (i < n) p[i] = 0.f;
}

// Wh[o][e*1024+d] = aW[e][d][o] (o<8) | cW[e][d] (o==8); bf16
__global__ __launch_bounds__(256)
void build_whead(const float* __restrict__ aW, const float* __restrict__ cW,
                 us* __restrict__ Wh)
{
  int i = blockIdx.x * 256 + threadIdx.x;
  if (i >= 9 * 8192) return;
  int o = i / 8192, k = i - o * 8192;
  float v = (o < 8) ? aW[(size_t)k * 8 + o] : cW[k];
  Wh[i] = f2bf(v);
}

// pbuf[i] += rdb[i&63]; optionally pbf[i] = bf16(pbuf[i])
__global__ __launch_bounds__(256)
void mk_pbf(float* __restrict__ pbuf, const float* __restrict__ rdb,
            us* __restrict__ pbf, int n)
{
  int i = blockIdx.x * 256 + threadIdx.x;
  if (i >= n) return;
  float v = pbuf[i] + rdb[i & 63];
  pbuf[i] = v;
  if (pbf) pbf[i] = f2bf(v);
}

// r_in = f_obs * z ; zr = relu(r_in).  zr may alias z.
__global__ __launch_bounds__(256)
void ew_rin_kernel(const us* fobs, const us* z, us* r_in, us* zr, int n4)
{
  int i = blockIdx.x * 256 + threadIdx.x;
  if (i >= n4) return;
  ushort4 fv = ((const ushort4*)fobs)[i];
  ushort4 zv = ((const ushort4*)z)[i];
  float r0 = bf2f(fv.x) * bf2f(zv.x);
  float r1 = bf2f(fv.y) * bf2f(zv.y);
  float r2 = bf2f(fv.z) * bf2f(zv.z);
  float r3 = bf2f(fv.w) * bf2f(zv.w);
  ushort4 rv = { f2bf(r0), f2bf(r1), f2bf(r2), f2bf(r3) };
  ushort4 bv = { f2bf(fmaxf(r0,0.f)), f2bf(fmaxf(r1,0.f)),
                 f2bf(fmaxf(r2,0.f)), f2bf(fmaxf(r3,0.f)) };
  ((ushort4*)r_in)[i] = rv;
  ((ushort4*)zr)[i] = bv;
}

// out = relu(u * r_in).  out may alias u.
__global__ __launch_bounds__(256)
void ew_umix_kernel(const us* u, const us* r_in, us* out, int n4)
{
  int i = blockIdx.x * 256 + threadIdx.x;
  if (i >= n4) return;
  ushort4 uv = ((const ushort4*)u)[i];
  ushort4 rv = ((const ushort4*)r_in)[i];
  ushort4 bv = { f2bf(fmaxf(bf2f(uv.x) * bf2f(rv.x), 0.f)),
                 f2bf(fmaxf(bf2f(uv.y) * bf2f(rv.y), 0.f)),
                 f2bf(fmaxf(bf2f(uv.z) * bf2f(rv.z), 0.f)),
                 f2bf(fmaxf(bf2f(uv.w) * bf2f(rv.w), 0.f)) };
  ((ushort4*)out)[i] = bv;
}

// softmax over groups of 8 contiguous floats
__global__ __launch_bounds__(256)
void softmax8_kernel(const float* __restrict__ p, float* __restrict__ probs, int total)
{
  int i = blockIdx.x * 256 + threadIdx.x;
  if (i >= total) return;
  const float4 lo = *(const float4*)(p + (size_t)i * 8);
  const float4 hi = *(const float4*)(p + (size_t)i * 8 + 4);
  float v[8] = { lo.x, lo.y, lo.z, lo.w, hi.x, hi.y, hi.z, hi.w };
  float m = v[0];
#pragma unroll
  for (int j = 1; j < 8; ++j) m = fmaxf(m, v[j]);
  float s = 0.f;
#pragma unroll
  for (int j = 0; j < 8; ++j) { v[j] = __expf(v[j] - m); s += v[j]; }
  float inv = 1.f / s;
  float4 olo = { v[0]*inv, v[1]*inv, v[2]*inv, v[3]*inv };
  float4 ohi = { v[4]*inv, v[5]*inv, v[6]*inv, v[7]*inv };
  *(float4*)(probs + (size_t)i * 8)     = olo;
  *(float4*)(probs + (size_t)i * 8 + 4) = ohi;
}

// out[i*sOutE + bl*sOutB + d] = sum_j P[bg,i,j]*he[j,bl,d]; block per local b
__global__ __launch_bounds__(256)
void mix_kernel(const us* __restrict__ he, const float* __restrict__ probs_l,
                us* __restrict__ xx, int b0, int chunkB,
                long long sOutE, long long sOutB)
{
  const int bl = blockIdx.x;
  const int bg = b0 + bl;
  __shared__ float P[64];
  if (threadIdx.x < 64) P[threadIdx.x] = probs_l[(size_t)bg * 64 + threadIdx.x];
  __syncthreads();
  const int t = threadIdx.x;
  const size_t es = (size_t)chunkB * 1024;
  const size_t rbase = (size_t)bl * 1024 + (size_t)t * 4;
  const size_t wbase = (size_t)bl * sOutB + (size_t)t * 4;
  float hv[8][4];
#pragma unroll
  for (int j = 0; j < 8; ++j) {
    ushort4 h4 = *(const ushort4*)(he + (size_t)j * es + rbase);
    hv[j][0] = bf2f(h4.x); hv[j][1] = bf2f(h4.y);
    hv[j][2] = bf2f(h4.z); hv[j][3] = bf2f(h4.w);
  }
#pragma unroll
  for (int i = 0; i < 8; ++i) {
    float o0 = 0.f, o1 = 0.f, o2 = 0.f, o3 = 0.f;
#pragma unroll
    for (int j = 0; j < 8; ++j) {
      float pij = P[i * 8 + j];
      o0 += pij * hv[j][0]; o1 += pij * hv[j][1];
      o2 += pij * hv[j][2]; o3 += pij * hv[j][3];
    }
    ushort4 ov = { f2bf(o0), f2bf(o1), f2bf(o2), f2bf(o3) };
    *(ushort4*)(xx + (size_t)i * sOutE + wbase) = ov;
  }
}

// out = [mu (B,8) | values (B)] from hout (B,9) + summed biases
__global__ __launch_bounds__(256)
void out_split(const float* __restrict__ hout,
               const float* __restrict__ ab, const float* __restrict__ cb,
               float* __restrict__ out, int B)
{
  int i = blockIdx.x * 256 + threadIdx.x;
  if (i >= B * 9) return;
  int b = i / 9, o = i - b * 9;
  float bsum = 0.f;
  if (o < 8) { for (int e = 0; e < 8; ++e) bsum += ab[e * 8 + o]; }
  else       { for (int e = 0; e < 8; ++e) bsum += cb[e]; }
  float v = hout[i] + bsum;
  if (o < 8) out[(size_t)b * 8 + o] = v;
  else       out[(size_t)B * 8 + b] = v;
}

// ---------------------------------------------------------------------------
extern "C" void kernel_launch(void* const* d_in, const int* in_sizes, int n_in,
                              void* d_out, int out_size, void* d_ws, size_t ws_size,
                              hipStream_t stream)
{
  const float* x   = (const float*)d_in[0];
  const float* sW1 = (const float*)d_in[1];
  const float* sb1 = (const float*)d_in[2];
  const float* sW2 = (const float*)d_in[3];
  const float* sb2 = (const float*)d_in[4];
  const float* sW3 = (const float*)d_in[5];
  const float* sb3 = (const float*)d_in[6];
  const float* tW  = (const float*)d_in[7];
  const float* tb  = (const float*)d_in[8];
  const float* rdW = (const float*)d_in[9];
  const float* rdb = (const float*)d_in[10];
  const float* ruW = (const float*)d_in[11];
  const float* rub = (const float*)d_in[12];
  const float* eW  = (const float*)d_in[13];
  const float* eb  = (const float*)d_in[14];
  const float* aW  = (const float*)d_in[15];
  const float* ab  = (const float*)d_in[16];
  const float* cW  = (const float*)d_in[17];
  const float* cb  = (const float*)d_in[18];
  float* out = (float*)d_out;

  const int B = 8192;
  const size_t BD = (size_t)B * 1024;
  char* ws = (char*)d_ws;

  // ---- arena: persistent region -------------------------------------------
  size_t o = 0;
  auto take = [&](size_t bytes) { size_t r = o; o = (o + bytes + 255) & ~(size_t)255; return r; };
  const size_t off_s1t  = take((size_t)512 * 128 * 2);
  const size_t off_s2t  = take((size_t)512 * 512 * 2);
  const size_t off_s3t  = take((size_t)1024 * 512 * 2);
  const size_t off_tWt  = take((size_t)1024 * 64 * 2);
  const size_t off_rdt  = take((size_t)2 * 64 * 1024 * 2);
  const size_t off_rut  = take((size_t)1024 * 64 * 2);
  const size_t off_eWt  = take((size_t)16 * 1024 * 1024 * 2);
  const size_t off_fobs = take(BD * 2);
  const size_t off_probs= take((size_t)2 * B * 64 * 4);
  const size_t off_Wh   = take((size_t)9 * 8192 * 2);
  const size_t off_hout = take((size_t)B * 9 * 4);
  const size_t P0 = o;
  // ---- scratch overlays (routing phase) -----------------------------------
  const size_t off_rin  = P0;                 // also h1
  const size_t off_rbuf = off_rin + BD * 2;   // also h2, z, u
  const size_t off_pbuf = off_rbuf + BD * 2;
  const size_t off_pbf  = off_pbuf + (size_t)2 * B * 64 * 4;
  const size_t off_obs  = off_pbf + (size_t)B * 64 * 2;
  const size_t off_task = off_obs + (size_t)B * 128 * 2;
  const size_t routing_end = off_task + (size_t)B * 64 * 2;

  // ---- expert-stage chunk selection (he/xx overlay scratch at P0) ---------
  int chunk = 0;
  const int cands[4] = {8192, 4096, 2048, 1024};
  for (int i = 0; i < 4; ++i) {
    size_t need = P0 + (size_t)cands[i] * 32768;  // he + xx
    if (need <= ws_size) { chunk = cands[i]; break; }
  }
  if (!chunk || routing_end > ws_size) return;

  us* s1t  = (us*)(ws + off_s1t);
  us* s2t  = (us*)(ws + off_s2t);
  us* s3t  = (us*)(ws + off_s3t);
  us* tWt  = (us*)(ws + off_tWt);
  us* rdt  = (us*)(ws + off_rdt);
  us* rut  = (us*)(ws + off_rut);
  us* eWt  = (us*)(ws + off_eWt);
  us* fobs = (us*)(ws + off_fobs);
  float* probs = (float*)(ws + off_probs);
  us* Wh   = (us*)(ws + off_Wh);
  float* hout = (float*)(ws + off_hout);
  us* rin  = (us*)(ws + off_rin);
  us* rbuf = (us*)(ws + off_rbuf);
  float* pbuf = (float*)(ws + off_pbuf);
  us* pbf  = (us*)(ws + off_pbf);
  us* obs_bf  = (us*)(ws + off_obs);
  us* task_bf = (us*)(ws + off_task);
  us* h1 = rin;
  us* h2 = rbuf;
  us* he = (us*)(ws + P0);
  us* xx = (us*)(ws + P0 + (size_t)chunk * 16384);  // also xxf (b-major)

  // ---- weight conversion / input split ------------------------------------
  split_convert_x<<<dim3((B * 192 + 255) / 256), 256, 0, stream>>>(x, obs_bf, task_bf, B * 192);
  transpose_bf16<<<dim3(16, 4, 1),  256, 0, stream>>>(sW1, s1t, 128, 512, 0, 0);
  transpose_bf16<<<dim3(16, 16, 1), 256, 0, stream>>>(sW2, s2t, 512, 512, 0, 0);
  transpose_bf16<<<dim3(32, 16, 1), 256, 0, stream>>>(sW3, s3t, 512, 1024, 0, 0);
  transpose_bf16<<<dim3(32, 2, 1),  256, 0, stream>>>(tW, tWt, 64, 1024, 0, 0);
  transpose_bf16<<<dim3(2, 32, 2),  256, 0, stream>>>(rdW, rdt, 1024, 64, 65536, 65536);
  transpose_bf16<<<dim3(32, 2, 1),  256, 0, stream>>>(ruW, rut, 64, 1024, 0, 0);
  transpose_bf16<<<dim3(32, 32, 16), 256, 0, stream>>>(eW, eWt, 1024, 1024, 1048576, 1048576);
  build_whead<<<dim3((9 * 8192 + 255) / 256), 256, 0, stream>>>(aW, cW, Wh);
  zero_f32<<<dim3((B * 9 + 255) / 256), 256, 0, stream>>>(hout, B * 9);
  zero_f32<<<dim3((2 * B * 64 + 255) / 256), 256, 0, stream>>>(pbuf, 2 * B * 64);

  const int n4 = (int)(BD / 4);
  const int ewg = (n4 + 255) / 256;

  // ---- shared MLP ---------------------------------------------------------
  gemm_bt<<<dim3(4, 64, 1), 256, 0, stream>>>(obs_bf, s1t, sb1, h1, (float*)0,
      B, 512, 128, 128, 128, 0, 0, 0, 0, 1, 0);
  gemm_bt<<<dim3(4, 64, 1), 256, 0, stream>>>(h1, s2t, sb2, h2, (float*)0,
      B, 512, 512, 512, 512, 0, 0, 0, 0, 1, 0);
  gemm_bt<<<dim3(8, 64, 1), 256, 0, stream>>>(h2, s3t, sb3, fobs, (float*)0,
      B, 1024, 512, 512, 512, 0, 0, 0, 0, 0, 0);
  gemm_bt<<<dim3(8, 64, 1), 256, 0, stream>>>(task_bf, tWt, tb, rbuf, (float*)0,
      B, 1024, 64, 64, 64, 0, 0, 0, 0, 1, 0);            // z -> rbuf
  ew_rin_kernel<<<dim3(ewg), 256, 0, stream>>>(fobs, rbuf, rin, rbuf, n4);

  // ---- routing (layers 0,1; layer 2 is dead code) -------------------------
  // p0: split-K=4 atomic into pbuf[0]
  gemm_bt<<<dim3(1, 64, 4), 256, 0, stream>>>(rbuf, rdt, (const float*)0,
      (us*)0, pbuf, B, 64, 256, 1024, 1024, 256, 256, 0, 0, 0, 1);
  mk_pbf<<<dim3((B * 64 + 255) / 256), 256, 0, stream>>>(pbuf, rdb, pbf, B * 64);
  gemm_bt<<<dim3(8, 64, 1), 256, 0, stream>>>(pbf, rut, rub, rbuf, (float*)0,
      B, 1024, 64, 64, 64, 0, 0, 0, 0, 0, 0);            // u -> rbuf
  ew_umix_kernel<<<dim3(ewg), 256, 0, stream>>>(rbuf, rin, rbuf, n4);
  // p1
  gemm_bt<<<dim3(1, 64, 4), 256, 0, stream>>>(rbuf, rdt + 65536, (const float*)0,
      (us*)0, pbuf + (size_t)B * 64, B, 64, 256, 1024, 1024, 256, 256, 0, 0, 0, 1);
  mk_pbf<<<dim3((B * 64 + 255) / 256), 256, 0, stream>>>(pbuf + (size_t)B * 64,
      rdb + 64, (us*)0, B * 64);
  softmax8_kernel<<<dim3((2 * B * 8 + 255) / 256), 256, 0, stream>>>(pbuf, probs, 2 * B * 8);

  // ---- expert stage, chunked over batch -----------------------------------
  const long long sHE = (long long)chunk * 1024;
  for (int b0 = 0; b0 < B; b0 += chunk) {
    gemm_bt<<<dim3(8, chunk / 128, 8), 256, 0, stream>>>(
        fobs + (size_t)b0 * 1024, eWt, eb, he, (float*)0,
        chunk, 1024, 1024, 1024, 1024, 0, 1048576, 1024, sHE, 1, 0);
    mix_kernel<<<dim3(chunk), 256, 0, stream>>>(he, probs, xx, b0, chunk, sHE, 1024);
    gemm_bt<<<dim3(8, chunk / 128, 8), 256, 0, stream>>>(
        xx, eWt + (size_t)8 * 1048576, eb + 8192, he, (float*)0,
        chunk, 1024, 1024, 1024, 1024, sHE, 1048576, 1024, sHE, 1, 0);
    // xx reused in b-major layout [bl][e*1024+d] for the head GEMM
    mix_kernel<<<dim3(chunk), 256, 0, stream>>>(he, probs + (size_t)B * 64, xx,
        b0, chunk, 1024, 8192);
    // heads: M=chunk, N=9, K=8192, split-K=4 atomic into hout
    gemm_bt<<<dim3(1, chunk / 128, 4), 256, 0, stream>>>(
        xx, Wh, (const float*)0, (us*)0, hout + (size_t)b0 * 9,
        chunk, 9, 2048, 8192, 8192, 2048, 2048, 0, 0, 0, 1);
  }
  out_split<<<dim3((B * 9 + 255) / 256), 256, 0, stream>>>(hout, ab, cb, out, B);
}

// Round 4
// 849.743 us; speedup vs baseline: 1.3544x; 1.0920x over previous
//
#include <hip/hip_runtime.h>

// ---------------------------------------------------------------------------
// SharedPPOSoftModularizedMLP on MI355X (gfx950)
// B=8192, OBS=128, TASK=64, D=1024, E=8, L=4
// bf16 MFMA (16x16x32), fp32 accumulate.
// R4: XCD chunk swizzle (weights L2-resident per XCD); vectorized bf16
//     epilogue via LDS (dwordx4 stores); elementwise fused into epilogues.
// ---------------------------------------------------------------------------

typedef __attribute__((ext_vector_type(8))) short short8;   // 8 x bf16 frag
typedef __attribute__((ext_vector_type(4))) float floatx4;  // MFMA acc
typedef unsigned short us;

__device__ __forceinline__ us f2bf(float f) {
  union { float f; unsigned u; } v; v.f = f;
  return (us)((v.u + 0x7FFFu + ((v.u >> 16) & 1u)) >> 16);  // RNE
}
__device__ __forceinline__ float bf2f(us h) {
  union { unsigned u; float f; } v; v.u = ((unsigned)h) << 16;
  return v.f;
}

// async global->LDS, 16B per lane; lds dest = wave-uniform base + lane*16
__device__ __forceinline__ void g2lds16(const void* g, void* l) {
  __builtin_amdgcn_global_load_lds(
      (const __attribute__((address_space(1))) void*)g,
      (__attribute__((address_space(3))) void*)l, 16, 0, 0);
}

// ---------------------------------------------------------------------------
// C[M,N] = post(act(A[M,K]@Bt[N,K]^T + bias[N])); A,Bt bf16.
// post: optional elementwise Mul[M,N] (bf16), then optional relu2.
// Cb2 != 0: Cb = value, Cb2 = relu(value) (dual output, for r_in/zr).
// atomic: split-K over blockIdx.z, atomicAdd into Cf (no bias/relu/Cb).
// grid=(ceil(N/128), M/128, Z); Z = expert batch or k-chunk (atomic mode).
// XCD chunk swizzle applied when total blocks % 8 == 0.
// ---------------------------------------------------------------------------
__global__ __launch_bounds__(256)
void gemm_bt(const us* __restrict__ A, const us* __restrict__ Bt,
             const float* __restrict__ bias,
             us* __restrict__ Cb, us* __restrict__ Cb2,
             float* __restrict__ Cf, const us* __restrict__ Mul,
             int M, int N, int K, int lda, int ldb,
             long long sA, long long sB, long long sBias, long long sC,
             int relu, int relu2, int atomic)
{
  // ---- XCD chunk swizzle: give each XCD a contiguous slice of work ----
  int bx = blockIdx.x, by = blockIdx.y, bz = blockIdx.z;
  {
    const int gx = gridDim.x, gy = gridDim.y;
    const int total = gx * gy * gridDim.z;
    if ((total & 7) == 0) {
      int L = bx + gx * (by + gy * bz);
      int per = total >> 3;
      int w = (L & 7) * per + (L >> 3);   // XCD id * chunk + slot
      bx = w % gx; w /= gx;
      by = w % gy; bz = w / gy;
    }
  }

  const int e = bz;
  const us* Ab = A + (size_t)e * sA;
  const us* Bb = Bt + (size_t)e * sB;
  const float* biasb = bias ? bias + (size_t)e * sBias : (const float*)0;

  const int m0 = by * 128;
  const int n0 = bx * 128;
  const int tid = threadIdx.x;
  const int wave = tid >> 6;
  const int lane = tid & 63;
  const int wm = (wave >> 1) * 64;
  const int wn = (wave & 1) * 64;
  const int lr = lane & 15;
  const int lq = lane >> 4;

  // staging: A = smem[0..8191], B = smem[8192..16383]  (us units)
  // epilogue tile: smem[0..17407] as [128][136] us
  __shared__ __align__(16) us smem[128 * 136 + 64];
  us* ldsA = smem;
  us* ldsB = smem + 128 * 64;

  floatx4 acc[4][4];
#pragma unroll
  for (int i = 0; i < 4; ++i)
#pragma unroll
    for (int j = 0; j < 4; ++j) acc[i][j] = (floatx4){0.f, 0.f, 0.f, 0.f};

  for (int k0 = 0; k0 < K; k0 += 64) {
#pragma unroll
    for (int c = 0; c < 4; ++c) {
      int slot = c * 256 + tid;               // physical 16B chunk
      int r = slot >> 3;
      int s = (slot & 7) ^ (r & 7);           // logical slab (XOR swizzle)
      int ubase = (c * 256 + wave * 64) * 8;  // wave-uniform LDS base (us)
      const us* ga = Ab + (size_t)(m0 + r) * lda + k0 + s * 8;
      g2lds16(ga, ldsA + ubase);
      int nrow = n0 + r; if (nrow > N - 1) nrow = N - 1;  // clamp (N<128)
      const us* gb = Bb + (size_t)nrow * ldb + k0 + s * 8;
      g2lds16(gb, ldsB + ubase);
    }
    __syncthreads();

#pragma unroll
    for (int kk = 0; kk < 2; ++kk) {
      short8 af[4], bfr[4];
#pragma unroll
      for (int t = 0; t < 4; ++t) {
        int m = wm + t * 16 + lr;
        int s = kk * 4 + lq;
        af[t]  = *(const short8*)(ldsA + (size_t)(m * 8 + (s ^ (m & 7))) * 8);
        int n = wn + t * 16 + lr;
        bfr[t] = *(const short8*)(ldsB + (size_t)(n * 8 + (s ^ (n & 7))) * 8);
      }
#pragma unroll
      for (int mt = 0; mt < 4; ++mt)
#pragma unroll
        for (int nt = 0; nt < 4; ++nt)
          acc[mt][nt] = __builtin_amdgcn_mfma_f32_16x16x32_bf16(
              af[mt], bfr[nt], acc[mt][nt], 0, 0, 0);
    }
    __syncthreads();
  }

  // ---- epilogue.  C/D layout: col = lane&15, row = lq*4 + r ----
  const bool vecpath = (Cb && !Cf && (N % 128 == 0));
  if (vecpath) {
    // stage post-processed bf16 tile into LDS [128][136]
#pragma unroll
    for (int nt = 0; nt < 4; ++nt) {
      int coll = wn + nt * 16 + lr;
      int col = n0 + coll;
      float bv = biasb ? biasb[col] : 0.f;
#pragma unroll
      for (int mt = 0; mt < 4; ++mt) {
        int rowl = wm + mt * 16 + lq * 4;
#pragma unroll
        for (int r = 0; r < 4; ++r) {
          float v = acc[mt][nt][r] + bv;
          if (relu) v = fmaxf(v, 0.f);
          if (Mul) v *= bf2f(Mul[(size_t)(m0 + rowl + r) * N + col]);
          if (relu2) v = fmaxf(v, 0.f);
          smem[(rowl + r) * 136 + coll] = f2bf(v);
        }
      }
    }
    __syncthreads();
    // read back row-major, 16B per lane; coalesced dwordx4 stores
#pragma unroll
    for (int c = 0; c < 8; ++c) {
      int sl = c * 256 + tid;
      int rowl = sl >> 4;
      int seg = sl & 15;
      short8 val = *(const short8*)(smem + rowl * 136 + seg * 8);
      size_t gidx = (size_t)e * sC + (size_t)(m0 + rowl) * N + n0 + seg * 8;
      *(short8*)(Cb + gidx) = val;
      if (Cb2) {
        short8 rl;
#pragma unroll
        for (int q = 0; q < 8; ++q) {
          us u = (us)val[q];
          rl[q] = (short)((u & 0x8000u) ? (us)0 : u);
        }
        *(short8*)(Cb2 + gidx) = rl;
      }
    }
  } else {
#pragma unroll
    for (int nt = 0; nt < 4; ++nt) {
      int col = n0 + wn + nt * 16 + lr;
      if (col >= N) continue;
      float bv = biasb ? biasb[col] : 0.f;
#pragma unroll
      for (int mt = 0; mt < 4; ++mt) {
        int row = m0 + wm + mt * 16 + lq * 4;
#pragma unroll
        for (int r = 0; r < 4; ++r) {
          float v = acc[mt][nt][r] + bv;
          if (relu) v = fmaxf(v, 0.f);
          if (Mul) v *= bf2f(Mul[(size_t)(row + r) * N + col]);
          if (relu2) v = fmaxf(v, 0.f);
          if (atomic) { atomicAdd(Cf + (size_t)(row + r) * N + col, v); continue; }
          size_t idx = (size_t)e * sC + (size_t)(row + r) * N + col;
          if (Cf) Cf[idx] = v;
          if (Cb) Cb[idx] = f2bf(v);
          if (Cb2) Cb2[idx] = f2bf(fmaxf(v, 0.f));
        }
      }
    }
  }
}

// fp32 [R,C] -> bf16 [C,R] (batched)
__global__ __launch_bounds__(256)
void transpose_bf16(const float* __restrict__ in, us* __restrict__ out,
                    int R, int C, long long inStride, long long outStride)
{
  const int b = blockIdx.z;
  in  += (size_t)b * inStride;
  out += (size_t)b * outStride;
  __shared__ float tile[32][33];
  const int tx = threadIdx.x & 31, ty = threadIdx.x >> 5;
  const int c0 = blockIdx.x * 32, r0 = blockIdx.y * 32;
#pragma unroll
  for (int i = 0; i < 4; ++i) {
    int r = r0 + ty + i * 8, c = c0 + tx;
    tile[ty + i * 8][tx] = (r < R && c < C) ? in[(size_t)r * C + c] : 0.f;
  }
  __syncthreads();
#pragma unroll
  for (int i = 0; i < 4; ++i) {
    int c = c0 + ty + i * 8, r = r0 + tx;
    if (c < C && r < R) out[(size_t)c * R + r] = f2bf(tile[tx][ty + i * 8]);
  }
}

// split x(B,192) -> obs bf16 (B,128), task bf16 (B,64)
__global__ __launch_bounds__(256)
void split_convert_x(const float* __restrict__ x, us* __restrict__ obs,
                     us* __restrict__ task, int total)
{
  int i = blockIdx.x * 256 + threadIdx.x;
  if (i >= total) return;
  int b = i / 192, c = i - b * 192;
  us v = f2bf(x[i]);
  if (c < 128) obs[(size_t)b * 128 + c] = v;
  else         task[(size_t)b * 64 + (c - 128)] = v;
}

__global__ __launch_bounds__(256)
void zero_f32(float* __restrict__ p, int n)
{
  int i = blockIdx.x * 256 + threadIdx.x;
  if (i < n) p[i] = 0.f;
}

// Wh[o][e*1024+d] = aW[e][d][o] (o<8) | cW[e][d] (o==8); bf16
__global__ __launch_bounds__(256)
void build_whead(const float* __restrict__ aW, const float* __restrict__ cW,
                 us* __restrict__ Wh)
{
  int i = blockIdx.x * 256 + threadIdx.x;
  if (i >= 9 * 8192) return;
  int o = i / 8192, k = i - o * 8192;
  float v = (o < 8) ? aW[(size_t)k * 8 + o] : cW[k];
  Wh[i] = f2bf(v);
}

// pbuf[i] += rdb[i&63]; optionally pbf[i] = bf16(pbuf[i])
__global__ __launch_bounds__(256)
void mk_pbf(float* __restrict__ pbuf, const float* __restrict__ rdb,
            us* __restrict__ pbf, int n)
{
  int i = blockIdx.x * 256 + threadIdx.x;
  if (i >= n) return;
  float v = pbuf[i] + rdb[i & 63];
  pbuf[i] = v;
  if (pbf) pbf[i] = f2bf(v);
}

// softmax over groups of 8 contiguous floats
__global__ __launch_bounds__(256)
void softmax8_kernel(const float* __restrict__ p, float* __restrict__ probs, int total)
{
  int i = blockIdx.x * 256 + threadIdx.x;
  if (i >= total) return;
  const float4 lo = *(const float4*)(p + (size_t)i * 8);
  const float4 hi = *(const float4*)(p + (size_t)i * 8 + 4);
  float v[8] = { lo.x, lo.y, lo.z, lo.w, hi.x, hi.y, hi.z, hi.w };
  float m = v[0];
#pragma unroll
  for (int j = 1; j < 8; ++j) m = fmaxf(m, v[j]);
  float s = 0.f;
#pragma unroll
  for (int j = 0; j < 8; ++j) { v[j] = __expf(v[j] - m); s += v[j]; }
  float inv = 1.f / s;
  float4 olo = { v[0]*inv, v[1]*inv, v[2]*inv, v[3]*inv };
  float4 ohi = { v[4]*inv, v[5]*inv, v[6]*inv, v[7]*inv };
  *(float4*)(probs + (size_t)i * 8)     = olo;
  *(float4*)(probs + (size_t)i * 8 + 4) = ohi;
}

// out[i*sOutE + bl*sOutB + d] = sum_j P[bg,i,j]*he[j,bl,d]; block per local b
__global__ __launch_bounds__(256)
void mix_kernel(const us* __restrict__ he, const float* __restrict__ probs_l,
                us* __restrict__ xx, int b0, int chunkB,
                long long sOutE, long long sOutB)
{
  const int bl = blockIdx.x;
  const int bg = b0 + bl;
  __shared__ float P[64];
  if (threadIdx.x < 64) P[threadIdx.x] = probs_l[(size_t)bg * 64 + threadIdx.x];
  __syncthreads();
  const int t = threadIdx.x;
  const size_t es = (size_t)chunkB * 1024;
  const size_t rbase = (size_t)bl * 1024 + (size_t)t * 4;
  const size_t wbase = (size_t)bl * sOutB + (size_t)t * 4;
  float hv[8][4];
#pragma unroll
  for (int j = 0; j < 8; ++j) {
    ushort4 h4 = *(const ushort4*)(he + (size_t)j * es + rbase);
    hv[j][0] = bf2f(h4.x); hv[j][1] = bf2f(h4.y);
    hv[j][2] = bf2f(h4.z); hv[j][3] = bf2f(h4.w);
  }
#pragma unroll
  for (int i = 0; i < 8; ++i) {
    float o0 = 0.f, o1 = 0.f, o2 = 0.f, o3 = 0.f;
#pragma unroll
    for (int j = 0; j < 8; ++j) {
      float pij = P[i * 8 + j];
      o0 += pij * hv[j][0]; o1 += pij * hv[j][1];
      o2 += pij * hv[j][2]; o3 += pij * hv[j][3];
    }
    ushort4 ov = { f2bf(o0), f2bf(o1), f2bf(o2), f2bf(o3) };
    *(ushort4*)(xx + (size_t)i * sOutE + wbase) = ov;
  }
}

// out = [mu (B,8) | values (B)] from hout (B,9) + summed biases
__global__ __launch_bounds__(256)
void out_split(const float* __restrict__ hout,
               const float* __restrict__ ab, const float* __restrict__ cb,
               float* __restrict__ out, int B)
{
  int i = blockIdx.x * 256 + threadIdx.x;
  if (i >= B * 9) return;
  int b = i / 9, o = i - b * 9;
  float bsum = 0.f;
  if (o < 8) { for (int e = 0; e < 8; ++e) bsum += ab[e * 8 + o]; }
  else       { for (int e = 0; e < 8; ++e) bsum += cb[e]; }
  float v = hout[i] + bsum;
  if (o < 8) out[(size_t)b * 8 + o] = v;
  else       out[(size_t)B * 8 + b] = v;
}

// ---------------------------------------------------------------------------
extern "C" void kernel_launch(void* const* d_in, const int* in_sizes, int n_in,
                              void* d_out, int out_size, void* d_ws, size_t ws_size,
                              hipStream_t stream)
{
  const float* x   = (const float*)d_in[0];
  const float* sW1 = (const float*)d_in[1];
  const float* sb1 = (const float*)d_in[2];
  const float* sW2 = (const float*)d_in[3];
  const float* sb2 = (const float*)d_in[4];
  const float* sW3 = (const float*)d_in[5];
  const float* sb3 = (const float*)d_in[6];
  const float* tW  = (const float*)d_in[7];
  const float* tb  = (const float*)d_in[8];
  const float* rdW = (const float*)d_in[9];
  const float* rdb = (const float*)d_in[10];
  const float* ruW = (const float*)d_in[11];
  const float* rub = (const float*)d_in[12];
  const float* eW  = (const float*)d_in[13];
  const float* eb  = (const float*)d_in[14];
  const float* aW  = (const float*)d_in[15];
  const float* ab  = (const float*)d_in[16];
  const float* cW  = (const float*)d_in[17];
  const float* cb  = (const float*)d_in[18];
  float* out = (float*)d_out;

  const int B = 8192;
  const size_t BD = (size_t)B * 1024;
  char* ws = (char*)d_ws;

  // ---- arena: persistent region -------------------------------------------
  size_t o = 0;
  auto take = [&](size_t bytes) { size_t r = o; o = (o + bytes + 255) & ~(size_t)255; return r; };
  const size_t off_s1t  = take((size_t)512 * 128 * 2);
  const size_t off_s2t  = take((size_t)512 * 512 * 2);
  const size_t off_s3t  = take((size_t)1024 * 512 * 2);
  const size_t off_tWt  = take((size_t)1024 * 64 * 2);
  const size_t off_rdt  = take((size_t)2 * 64 * 1024 * 2);
  const size_t off_rut  = take((size_t)1024 * 64 * 2);
  const size_t off_eWt  = take((size_t)16 * 1024 * 1024 * 2);
  const size_t off_fobs = take(BD * 2);
  const size_t off_probs= take((size_t)2 * B * 64 * 4);
  const size_t off_Wh   = take((size_t)9 * 8192 * 2);
  const size_t off_hout = take((size_t)B * 9 * 4);
  const size_t P0 = o;
  // ---- scratch overlays (routing phase) -----------------------------------
  const size_t off_rin  = P0;                 // also h1
  const size_t off_rbuf = off_rin + BD * 2;   // also h2, u
  const size_t off_pbuf = off_rbuf + BD * 2;
  const size_t off_pbf  = off_pbuf + (size_t)2 * B * 64 * 4;
  const size_t off_obs  = off_pbf + (size_t)B * 64 * 2;
  const size_t off_task = off_obs + (size_t)B * 128 * 2;
  const size_t routing_end = off_task + (size_t)B * 64 * 2;

  // ---- expert-stage chunk selection (he/xx overlay scratch at P0) ---------
  int chunk = 0;
  const int cands[4] = {8192, 4096, 2048, 1024};
  for (int i = 0; i < 4; ++i) {
    size_t need = P0 + (size_t)cands[i] * 32768;  // he + xx
    if (need <= ws_size) { chunk = cands[i]; break; }
  }
  if (!chunk || routing_end > ws_size) return;

  us* s1t  = (us*)(ws + off_s1t);
  us* s2t  = (us*)(ws + off_s2t);
  us* s3t  = (us*)(ws + off_s3t);
  us* tWt  = (us*)(ws + off_tWt);
  us* rdt  = (us*)(ws + off_rdt);
  us* rut  = (us*)(ws + off_rut);
  us* eWt  = (us*)(ws + off_eWt);
  us* fobs = (us*)(ws + off_fobs);
  float* probs = (float*)(ws + off_probs);
  us* Wh   = (us*)(ws + off_Wh);
  float* hout = (float*)(ws + off_hout);
  us* rin  = (us*)(ws + off_rin);
  us* rbuf = (us*)(ws + off_rbuf);
  float* pbuf = (float*)(ws + off_pbuf);
  us* pbf  = (us*)(ws + off_pbf);
  us* obs_bf  = (us*)(ws + off_obs);
  us* task_bf = (us*)(ws + off_task);
  us* h1 = rin;
  us* h2 = rbuf;
  us* he = (us*)(ws + P0);
  us* xx = (us*)(ws + P0 + (size_t)chunk * 16384);  // also b-major for head

  // ---- weight conversion / input split ------------------------------------
  split_convert_x<<<dim3((B * 192 + 255) / 256), 256, 0, stream>>>(x, obs_bf, task_bf, B * 192);
  transpose_bf16<<<dim3(16, 4, 1),  256, 0, stream>>>(sW1, s1t, 128, 512, 0, 0);
  transpose_bf16<<<dim3(16, 16, 1), 256, 0, stream>>>(sW2, s2t, 512, 512, 0, 0);
  transpose_bf16<<<dim3(32, 16, 1), 256, 0, stream>>>(sW3, s3t, 512, 1024, 0, 0);
  transpose_bf16<<<dim3(32, 2, 1),  256, 0, stream>>>(tW, tWt, 64, 1024, 0, 0);
  transpose_bf16<<<dim3(2, 32, 2),  256, 0, stream>>>(rdW, rdt, 1024, 64, 65536, 65536);
  transpose_bf16<<<dim3(32, 2, 1),  256, 0, stream>>>(ruW, rut, 64, 1024, 0, 0);
  transpose_bf16<<<dim3(32, 32, 16), 256, 0, stream>>>(eW, eWt, 1024, 1024, 1048576, 1048576);
  build_whead<<<dim3((9 * 8192 + 255) / 256), 256, 0, stream>>>(aW, cW, Wh);
  zero_f32<<<dim3((B * 9 + 255) / 256), 256, 0, stream>>>(hout, B * 9);
  zero_f32<<<dim3((2 * B * 64 + 255) / 256), 256, 0, stream>>>(pbuf, 2 * B * 64);

  // ---- shared MLP ---------------------------------------------------------
  gemm_bt<<<dim3(4, 64, 1), 256, 0, stream>>>(obs_bf, s1t, sb1, h1, (us*)0,
      (float*)0, (const us*)0, B, 512, 128, 128, 128, 0, 0, 0, 0, 1, 0, 0);
  gemm_bt<<<dim3(4, 64, 1), 256, 0, stream>>>(h1, s2t, sb2, h2, (us*)0,
      (float*)0, (const us*)0, B, 512, 512, 512, 512, 0, 0, 0, 0, 1, 0, 0);
  gemm_bt<<<dim3(8, 64, 1), 256, 0, stream>>>(h2, s3t, sb3, fobs, (us*)0,
      (float*)0, (const us*)0, B, 1024, 512, 512, 512, 0, 0, 0, 0, 0, 0, 0);
  // z-GEMM fused: rin = relu(task@tW+tb)*fobs ; rbuf = relu(rin)
  gemm_bt<<<dim3(8, 64, 1), 256, 0, stream>>>(task_bf, tWt, tb, rin, rbuf,
      (float*)0, fobs, B, 1024, 64, 64, 64, 0, 0, 0, 0, 1, 0, 0);

  // ---- routing (layers 0,1; layer 2 is dead code) -------------------------
  gemm_bt<<<dim3(1, 64, 4), 256, 0, stream>>>(rbuf, rdt, (const float*)0,
      (us*)0, (us*)0, pbuf, (const us*)0,
      B, 64, 256, 1024, 1024, 256, 256, 0, 0, 0, 0, 1);       // p0 split-K
  mk_pbf<<<dim3((B * 64 + 255) / 256), 256, 0, stream>>>(pbuf, rdb, pbf, B * 64);
  // u-GEMM fused: rbuf = relu((pbf@ruW+rub) * rin)
  gemm_bt<<<dim3(8, 64, 1), 256, 0, stream>>>(pbf, rut, rub, rbuf, (us*)0,
      (float*)0, rin, B, 1024, 64, 64, 64, 0, 0, 0, 0, 0, 1, 0);
  gemm_bt<<<dim3(1, 64, 4), 256, 0, stream>>>(rbuf, rdt + 65536, (const float*)0,
      (us*)0, (us*)0, pbuf + (size_t)B * 64, (const us*)0,
      B, 64, 256, 1024, 1024, 256, 256, 0, 0, 0, 0, 1);       // p1 split-K
  mk_pbf<<<dim3((B * 64 + 255) / 256), 256, 0, stream>>>(pbuf + (size_t)B * 64,
      rdb + 64, (us*)0, B * 64);
  softmax8_kernel<<<dim3((2 * B * 8 + 255) / 256), 256, 0, stream>>>(pbuf, probs, 2 * B * 8);

  // ---- expert stage, chunked over batch -----------------------------------
  const long long sHE = (long long)chunk * 1024;
  for (int b0 = 0; b0 < B; b0 += chunk) {
    gemm_bt<<<dim3(8, chunk / 128, 8), 256, 0, stream>>>(
        fobs + (size_t)b0 * 1024, eWt, eb, he, (us*)0, (float*)0, (const us*)0,
        chunk, 1024, 1024, 1024, 1024, 0, 1048576, 1024, sHE, 1, 0, 0);
    mix_kernel<<<dim3(chunk), 256, 0, stream>>>(he, probs, xx, b0, chunk, sHE, 1024);
    gemm_bt<<<dim3(8, chunk / 128, 8), 256, 0, stream>>>(
        xx, eWt + (size_t)8 * 1048576, eb + 8192, he, (us*)0, (float*)0, (const us*)0,
        chunk, 1024, 1024, 1024, 1024, sHE, 1048576, 1024, sHE, 1, 0, 0);
    // xx reused in b-major layout [bl][e*1024+d] for the head GEMM
    mix_kernel<<<dim3(chunk), 256, 0, stream>>>(he, probs + (size_t)B * 64, xx,
        b0, chunk, 1024, 8192);
    // heads: M=chunk, N=9, K=8192, split-K=4 atomic into hout
    gemm_bt<<<dim3(1, chunk / 128, 4), 256, 0, stream>>>(
        xx, Wh, (const float*)0, (us*)0, (us*)0, hout + (size_t)b0 * 9, (const us*)0,
        chunk, 9, 2048, 8192, 8192, 2048, 2048, 0, 0, 0, 0, 1);
  }
  out_split<<<dim3((B * 9 + 255) / 256), 256, 0, stream>>>(hout, ab, cb, out, B);
}